// Round 5
// baseline (192.802 us; speedup 1.0000x reference)
//
#include <hip/hip_runtime.h>
#include <math.h>

// Problem constants
constexpr int B_  = 16;
constexpr int P_  = 1024;
constexpr int Q_  = 512;
constexpr int PD_ = 768;   // p_dim
constexpr int QD_ = 768;   // q_dim
constexpr int CD_ = 1536;  // q_dim + p_dim

#define HUGE_NEG (-1e8f)

typedef __attribute__((ext_vector_type(8))) _Float16 f16x8;
typedef __attribute__((ext_vector_type(4))) _Float16 f16x4;
typedef __attribute__((ext_vector_type(4))) float f32x4;

// async global->LDS DMA, 16B/lane: HW writes lds_base + lane*16 (wave-linear).
__device__ __forceinline__ void dma16(const void* g, void* l) {
  __builtin_amdgcn_global_load_lds((__attribute__((address_space(1))) void*)g,
                                   (__attribute__((address_space(3))) void*)l,
                                   16, 0, 0);
}

// ---------------------------------------------------------------------------
// fp32 -> fp16 convert, 8 elems/thread (W only).
// ---------------------------------------------------------------------------
__global__ __launch_bounds__(256) void k_cvt(const float* __restrict__ src,
                                             _Float16* __restrict__ dst, int n8) {
  int i = blockIdx.x * 256 + threadIdx.x;
  if (i >= n8) return;
  float4 a = ((const float4*)src)[2 * i];
  float4 b = ((const float4*)src)[2 * i + 1];
  f16x8 o = {(_Float16)a.x, (_Float16)a.y, (_Float16)a.z, (_Float16)a.w,
             (_Float16)b.x, (_Float16)b.y, (_Float16)b.z, (_Float16)b.w};
  ((f16x8*)dst)[i] = o;
}

// ---------------------------------------------------------------------------
// Fused convert+transpose: read fp32 src[b][R][C] once ->
//   dst16[b][R][C] fp16 (row-major) AND dstT[b][C][R] fp16 (transposed).
// 64x64 tiles. grid = (R/64, C/64, B)
// ---------------------------------------------------------------------------
__global__ __launch_bounds__(256) void k_prep(const float* __restrict__ src,
                                              _Float16* __restrict__ dst16,
                                              _Float16* __restrict__ dstT,
                                              int R, int C, size_t tBatch) {
  __shared__ _Float16 T[64][72];
  int r0 = blockIdx.x * 64, c0 = blockIdx.y * 64, b = blockIdx.z;
  const float* S = src + (size_t)b * R * C;
  _Float16* D16 = dst16 + (size_t)b * R * C;
  int tid = threadIdx.x;
  int rr = tid >> 4;
  int cc = (tid & 15) * 4;
#pragma unroll
  for (int k = 0; k < 4; ++k) {
    int r = rr + k * 16;
    float4 v = *(const float4*)(S + (size_t)(r0 + r) * C + c0 + cc);
    f16x4 h = {(_Float16)v.x, (_Float16)v.y, (_Float16)v.z, (_Float16)v.w};
    *(f16x4*)(D16 + (size_t)(r0 + r) * C + c0 + cc) = h;
    T[cc + 0][r] = h[0];
    T[cc + 1][r] = h[1];
    T[cc + 2][r] = h[2];
    T[cc + 3][r] = h[3];
  }
  __syncthreads();
  int cr = tid >> 2;
  int rc = (tid & 3) * 16;
  _Float16* D = dstT + (size_t)b * tBatch + (size_t)(c0 + cr) * R + r0;
  *(f16x8*)(D + rc) = *(f16x8*)&T[cr][rc];
  *(f16x8*)(D + rc + 8) = *(f16x8*)&T[cr][rc + 8];
}

// ---------------------------------------------------------------------------
// Merge row-stat partials (2 per row). grid = B*P/256.
// ---------------------------------------------------------------------------
__global__ __launch_bounds__(256) void k_rowmerge(
    const float* __restrict__ rpm, const float* __restrict__ rps,
    float* __restrict__ rowmax, float* __restrict__ rowsum) {
  int idx = blockIdx.x * 256 + threadIdx.x;  // b*P + p
  int b = idx >> 10, p = idx & 1023;
  float m0 = rpm[(b * 2 + 0) * P_ + p], m1 = rpm[(b * 2 + 1) * P_ + p];
  float s0 = rps[(b * 2 + 0) * P_ + p], s1 = rps[(b * 2 + 1) * P_ + p];
  float nm = fmaxf(m0, m1);
  rowmax[idx] = nm;
  rowsum[idx] = s0 * __expf(m0 - nm) + s1 * __expf(m1 - nm);
}

// ---------------------------------------------------------------------------
// Merge 8 column-stat partials. grid = (B, Q/256), block = 256.
// ---------------------------------------------------------------------------
__global__ __launch_bounds__(256) void k_colmerge(
    const float* __restrict__ pmax_part, const float* __restrict__ psum_part,
    float* __restrict__ colmax, float* __restrict__ colsum) {
  int b = blockIdx.x;
  int q = blockIdx.y * 256 + threadIdx.x;
  float m = -INFINITY;
#pragma unroll
  for (int z = 0; z < 8; ++z) m = fmaxf(m, pmax_part[(b * 8 + z) * Q_ + q]);
  float s = 0.f;
#pragma unroll
  for (int z = 0; z < 8; ++z)
    s += psum_part[(b * 8 + z) * Q_ + q] *
         __expf(pmax_part[(b * 8 + z) * Q_ + q] - m);
  colmax[b * Q_ + q] = m;
  colsum[b * Q_ + q] = s;
}

// ---------------------------------------------------------------------------
// Fused weights kernel: ONE read of aff produces
//   WP[b][p][q] = fp16(exp((qmask?-H:v)-rowmax[p]) / rowsum[p])   (row-major)
//   WQ[b][q][p] = fp16(exp((pmask?-H:v)-colmax[q]) / colsum[q])   (transposed)
// grid = (P/64, Q/64, B)
// ---------------------------------------------------------------------------
__global__ __launch_bounds__(256) void k_w(
    const float* __restrict__ aff, const int* __restrict__ pmask,
    const int* __restrict__ qmask, const float* __restrict__ rowmax,
    const float* __restrict__ rowsum, const float* __restrict__ colmax,
    const float* __restrict__ colsum, _Float16* __restrict__ WP,
    _Float16* __restrict__ WQ) {
  __shared__ _Float16 T[64][72];
  __shared__ float rmx[64], rin[64], cmx[64], cin[64];
  int p0 = blockIdx.x * 64, q0 = blockIdx.y * 64, b = blockIdx.z;
  int tid = threadIdx.x;
  if (tid < 64) {
    rmx[tid] = rowmax[b * P_ + p0 + tid];
    rin[tid] = 1.0f / rowsum[b * P_ + p0 + tid];
  } else if (tid < 128) {
    int t = tid - 64;
    cmx[t] = colmax[b * Q_ + q0 + t];
    cin[t] = 1.0f / colsum[b * Q_ + q0 + t];
  }
  __syncthreads();
  const float* A = aff + (size_t)b * P_ * Q_;
  const int* pm = pmask + b * P_;
  int rr = tid >> 4;
  int cc = (tid & 15) * 4;
  int4 qm4 = *(const int4*)(qmask + b * Q_ + q0 + cc);
  int qm[4] = {qm4.x, qm4.y, qm4.z, qm4.w};
#pragma unroll
  for (int k = 0; k < 4; ++k) {
    int r = rr + k * 16;
    int msk = pm[p0 + r];
    float4 v = *(const float4*)(A + (size_t)(p0 + r) * Q_ + q0 + cc);
    float vv[4] = {v.x, v.y, v.z, v.w};
    f16x4 wp;
#pragma unroll
    for (int j = 0; j < 4; ++j) {
      wp[j] = (_Float16)(__expf((qm[j] ? HUGE_NEG : vv[j]) - rmx[r]) * rin[r]);
      T[cc + j][r] =
          (_Float16)(__expf((msk ? HUGE_NEG : vv[j]) - cmx[cc + j]) * cin[cc + j]);
    }
    *(f16x4*)(WP + ((size_t)b * P_ + p0 + r) * Q_ + q0 + cc) = wp;
  }
  __syncthreads();
  int cr = tid >> 2;
  int rc = (tid & 3) * 16;
  _Float16* D = WQ + ((size_t)b * Q_ + q0 + cr) * P_ + p0;
  *(f16x8*)(D + rc) = *(f16x8*)&T[cr][rc];
  *(f16x8*)(D + rc + 8) = *(f16x8*)&T[cr][rc + 8];
}

// ---------------------------------------------------------------------------
// GEMM core v3: 128x256 tile, 4 waves (2Mx2N), wave-tile 64x128 (acc 4x8).
// BK=32, 3-buffer 2-deep prefetch, counted vmcnt (12/6/0), raw barriers,
// chunk-XOR LDS swizzle (pre-swizzled global source; same XOR on ds_read).
// C = A(rows i, k-contig, LDA) x B(rows j, k-contig, LDB)^T, fp32 acc.
// ---------------------------------------------------------------------------
template <int NT, int LDA, int LDB>
__device__ __forceinline__ void gemm_core(const _Float16* __restrict__ Ab,
                                          const _Float16* __restrict__ Bb,
                                          _Float16* As, _Float16* Bs,
                                          f32x4 (&acc)[4][8], int w, int l) {
  constexpr int ASZ = 128 * 32, BSZ = 256 * 32;
  int rowA = w * 32 + (l >> 2);
  int rowB = w * 64 + (l >> 2);
  int sA = ((l & 3) ^ ((l >> 3) & 3)) * 8;       // swizzled src chunk
  int fr = l & 15;
  int fsw = ((l >> 4) ^ ((fr >> 1) & 3)) * 8;    // swizzled read offset
  int wr = w >> 1, wc = w & 1;

  auto stage = [&](int buf, int t) {
    const _Float16* ga = Ab + (size_t)rowA * LDA + t * 32 + sA;
    _Float16* la = As + buf * ASZ + (w * 32) * 32;
    dma16(ga, la);
    dma16(ga + 16 * LDA, la + 16 * 32);
    const _Float16* gb = Bb + (size_t)rowB * LDB + t * 32 + sA;
    _Float16* lb = Bs + buf * BSZ + (w * 64) * 32;
    dma16(gb, lb);
    dma16(gb + 16 * LDB, lb + 16 * 32);
    dma16(gb + 32 * LDB, lb + 32 * 32);
    dma16(gb + 48 * LDB, lb + 48 * 32);
  };
  auto compute = [&](int buf) {
    const _Float16* A0 = As + buf * ASZ;
    const _Float16* B0 = Bs + buf * BSZ;
    f16x8 a[4];
#pragma unroll
    for (int m = 0; m < 4; ++m)
      a[m] = *(const f16x8*)(A0 + (wr * 64 + m * 16 + fr) * 32 + fsw);
#pragma unroll
    for (int n = 0; n < 8; ++n) {
      f16x8 bn = *(const f16x8*)(B0 + (wc * 128 + n * 16 + fr) * 32 + fsw);
#pragma unroll
      for (int m = 0; m < 4; ++m)
        acc[m][n] =
            __builtin_amdgcn_mfma_f32_16x16x32_f16(a[m], bn, acc[m][n], 0, 0, 0);
    }
  };

  stage(0, 0);
  stage(1, 1);
  int b0 = 0, b1 = 1, b2 = 2;
#pragma unroll 3
  for (int t = 0; t < NT - 2; ++t) {
    stage(b2, t + 2);
    asm volatile("s_waitcnt vmcnt(12)" ::: "memory");
    __builtin_amdgcn_s_barrier();
    __builtin_amdgcn_sched_barrier(0);
    compute(b0);
    __builtin_amdgcn_s_barrier();
    int tmp = b0; b0 = b1; b1 = b2; b2 = tmp;
  }
  asm volatile("s_waitcnt vmcnt(6)" ::: "memory");
  __builtin_amdgcn_s_barrier();
  __builtin_amdgcn_sched_barrier(0);
  compute(b0);
  __builtin_amdgcn_s_barrier();
  asm volatile("s_waitcnt vmcnt(0)" ::: "memory");
  __builtin_amdgcn_s_barrier();
  __builtin_amdgcn_sched_barrier(0);
  compute(b1);
}

// bijective XCD swizzle (nwg % 8 == 0); N-tile 256, M-tile 128
#define SWZ_DECODE(GX, GY)                                          \
  int lin = blockIdx.x + (GX) * (blockIdx.y + (GY) * blockIdx.z);   \
  constexpr int NWG = (GX) * (GY) * B_;                             \
  int w8 = (lin & 7) * (NWG / 8) + (lin >> 3);                      \
  int j0 = (w8 % (GX)) * 256;                                       \
  int t_ = w8 / (GX);                                               \
  int i0 = (t_ % (GY)) * 128;                                       \
  int b = t_ / (GY);

// ---------------------------------------------------------------------------
// K1: qp[b][q][pd] = sum_d q16[q][d] * W16[pd][d]. grid (PD/256, Q/128, B)
// ---------------------------------------------------------------------------
__global__ __launch_bounds__(256, 2) void k1_proj(
    const _Float16* __restrict__ q16, const _Float16* __restrict__ W16,
    _Float16* __restrict__ qp) {
  __shared__ alignas(16) _Float16 As[3 * 128 * 32];
  __shared__ alignas(16) _Float16 Bs[3 * 256 * 32];
  SWZ_DECODE(PD_ / 256, Q_ / 128)
  int tid = threadIdx.x, w = tid >> 6, l = tid & 63;
  f32x4 acc[4][8];
#pragma unroll
  for (int m = 0; m < 4; ++m)
#pragma unroll
    for (int n = 0; n < 8; ++n) acc[m][n] = (f32x4){0.f, 0.f, 0.f, 0.f};
  gemm_core<QD_ / 32, QD_, QD_>(q16 + (size_t)b * Q_ * QD_ + (size_t)i0 * QD_,
                                W16 + (size_t)j0 * QD_, As, Bs, acc, w, l);
  int wr = w >> 1, wc = w & 1, fr = l & 15, fq = l >> 4;
  _Float16* O = qp + (size_t)b * Q_ * PD_;
#pragma unroll
  for (int m = 0; m < 4; ++m) {
    int rl = wr * 64 + m * 16 + fq * 4;
#pragma unroll
    for (int n = 0; n < 8; ++n) {
      int cl = wc * 128 + n * 16 + fr;
#pragma unroll
      for (int r = 0; r < 4; ++r)
        O[(size_t)(i0 + rl + r) * PD_ + j0 + cl] = (_Float16)acc[m][n][r];
    }
  }
}

// ---------------------------------------------------------------------------
// K2: aff[b][p][q] = sum_d p16[p][d] * qp[q][d]. grid (Q/256, P/128, B)
// Epilogue: fp32 aff write + BOTH softmax-stat partials from the fp32 accs:
//   col partials (over this block's 128 p-rows, pmask) -> pmax/psum_part[z=i0/128]
//   row partials (over this block's 256 q-cols, qmask) -> rpm/rps[zj=j0/256]
// ---------------------------------------------------------------------------
__global__ __launch_bounds__(256, 2) void k2_aff(
    const _Float16* __restrict__ p16, const _Float16* __restrict__ qp,
    const int* __restrict__ pmask, const int* __restrict__ qmask,
    float* __restrict__ aff, float* __restrict__ pmax_part,
    float* __restrict__ psum_part, float* __restrict__ rpm,
    float* __restrict__ rps) {
  __shared__ alignas(16) _Float16 As[3 * 128 * 32];
  __shared__ alignas(16) _Float16 Bs[3 * 256 * 32];
  SWZ_DECODE(Q_ / 256, P_ / 128)
  int tid = threadIdx.x, w = tid >> 6, l = tid & 63;
  f32x4 acc[4][8];
#pragma unroll
  for (int m = 0; m < 4; ++m)
#pragma unroll
    for (int n = 0; n < 8; ++n) acc[m][n] = (f32x4){0.f, 0.f, 0.f, 0.f};
  gemm_core<PD_ / 32, PD_, PD_>(p16 + (size_t)b * P_ * PD_ + (size_t)i0 * PD_,
                                qp + (size_t)b * Q_ * PD_ + (size_t)j0 * PD_,
                                As, Bs, acc, w, l);
  int wr = w >> 1, wc = w & 1, fr = l & 15, fq = l >> 4;
  float* Cb = aff + (size_t)b * P_ * Q_;
#pragma unroll
  for (int m = 0; m < 4; ++m) {
    int rl = wr * 64 + m * 16 + fq * 4;
#pragma unroll
    for (int n = 0; n < 8; ++n) {
      int cl = wc * 128 + n * 16 + fr;
#pragma unroll
      for (int r = 0; r < 4; ++r)
        Cb[(size_t)(i0 + rl + r) * Q_ + j0 + cl] = acc[m][n][r];
    }
  }
  // ---- fused softmax stat partials ----
  const int* pmb = pmask + b * P_ + i0;
  unsigned pmbits = 0;
#pragma unroll
  for (int m = 0; m < 4; ++m)
#pragma unroll
    for (int r = 0; r < 4; ++r)
      pmbits |= (pmb[wr * 64 + m * 16 + fq * 4 + r] ? 1u : 0u) << (m * 4 + r);
  int qmv[8];
  {
    const int* qmb = qmask + b * Q_ + j0 + wc * 128 + fr;
#pragma unroll
    for (int n = 0; n < 8; ++n) qmv[n] = qmb[n * 16];
  }
  __syncthreads();  // all GEMM LDS reads done before scratch reuse
  float* scr = (float*)As;  // 6KB scratch
  float* cm_ = scr;         // [2][256]
  float* cs_ = scr + 512;
  float* rm_ = scr + 1024;  // [2][128]
  float* rs_ = scr + 1280;

  // column partials: reduce over 128 rows (m, r, fq-lanes, wr via LDS)
#pragma unroll
  for (int n = 0; n < 8; ++n) {
    float ml = -1e30f;
#pragma unroll
    for (int m = 0; m < 4; ++m)
#pragma unroll
      for (int r = 0; r < 4; ++r) {
        float v = ((pmbits >> (m * 4 + r)) & 1) ? HUGE_NEG : acc[m][n][r];
        ml = fmaxf(ml, v);
      }
    float sl = 0.f;
#pragma unroll
    for (int m = 0; m < 4; ++m)
#pragma unroll
      for (int r = 0; r < 4; ++r) {
        float v = ((pmbits >> (m * 4 + r)) & 1) ? HUGE_NEG : acc[m][n][r];
        sl += __expf(v - ml);
      }
#pragma unroll
    for (int off = 16; off <= 32; off <<= 1) {
      float om = __shfl_xor(ml, off);
      float os = __shfl_xor(sl, off);
      float nm = fmaxf(ml, om);
      sl = sl * __expf(ml - nm) + os * __expf(om - nm);
      ml = nm;
    }
    if (fq == 0) {
      int col = wc * 128 + n * 16 + fr;
      cm_[wr * 256 + col] = ml;
      cs_[wr * 256 + col] = sl;
    }
  }
  // row partials: reduce over 256 cols (n in-reg, fr-lanes, wc via LDS)
#pragma unroll
  for (int m = 0; m < 4; ++m)
#pragma unroll
    for (int r = 0; r < 4; ++r) {
      float ml = -1e30f;
#pragma unroll
      for (int n = 0; n < 8; ++n) {
        float v = qmv[n] ? HUGE_NEG : acc[m][n][r];
        ml = fmaxf(ml, v);
      }
      float sl = 0.f;
#pragma unroll
      for (int n = 0; n < 8; ++n) {
        float v = qmv[n] ? HUGE_NEG : acc[m][n][r];
        sl += __expf(v - ml);
      }
#pragma unroll
      for (int off = 1; off <= 8; off <<= 1) {
        float om = __shfl_xor(ml, off);
        float os = __shfl_xor(sl, off);
        float nm = fmaxf(ml, om);
        sl = sl * __expf(ml - nm) + os * __expf(om - nm);
        ml = nm;
      }
      if (fr == 0) {
        int row = wr * 64 + m * 16 + fq * 4 + r;
        rm_[wc * 128 + row] = ml;
        rs_[wc * 128 + row] = sl;
      }
    }
  __syncthreads();
  if (tid < 256) {
    float m0 = cm_[tid], m1 = cm_[256 + tid];
    float s0 = cs_[tid], s1 = cs_[256 + tid];
    float nm = fmaxf(m0, m1);
    float ns = s0 * __expf(m0 - nm) + s1 * __expf(m1 - nm);
    int z = i0 >> 7;
    pmax_part[(b * 8 + z) * Q_ + j0 + tid] = nm;
    psum_part[(b * 8 + z) * Q_ + j0 + tid] = ns;
  }
  if (tid < 128) {
    float m0 = rm_[tid], m1 = rm_[128 + tid];
    float s0 = rs_[tid], s1 = rs_[128 + tid];
    float nm = fmaxf(m0, m1);
    float ns = s0 * __expf(m0 - nm) + s1 * __expf(m1 - nm);
    int zj = j0 >> 8;
    rpm[(b * 2 + zj) * P_ + i0 + tid] = nm;
    rps[(b * 2 + zj) * P_ + i0 + tid] = ns;
  }
}

// ---------------------------------------------------------------------------
// K4: out2[b][q][d] = sum_p WQ[q][p] * pT[d][p]  (cinv pre-folded into WQ)
// Also writes candT[b][768+d][q] fp16. grid (PD/256, Q/128, B)
// ---------------------------------------------------------------------------
__global__ __launch_bounds__(256, 2) void k4_attn(
    const _Float16* __restrict__ WQ, const _Float16* __restrict__ pT,
    float* __restrict__ out2, _Float16* __restrict__ candT) {
  __shared__ alignas(16) _Float16 As[3 * 128 * 32];
  __shared__ alignas(16) _Float16 Bs[3 * 256 * 32];
  SWZ_DECODE(PD_ / 256, Q_ / 128)
  int tid = threadIdx.x, w = tid >> 6, l = tid & 63;
  f32x4 acc[4][8];
#pragma unroll
  for (int m = 0; m < 4; ++m)
#pragma unroll
    for (int n = 0; n < 8; ++n) acc[m][n] = (f32x4){0.f, 0.f, 0.f, 0.f};
  gemm_core<P_ / 32, P_, P_>(WQ + (size_t)b * Q_ * P_ + (size_t)i0 * P_,
                             pT + (size_t)b * PD_ * P_ + (size_t)j0 * P_, As,
                             Bs, acc, w, l);
  int wr = w >> 1, wc = w & 1, fr = l & 15, fq = l >> 4;
  float* Cb = out2 + (size_t)b * Q_ * PD_;
  _Float16* Tb = candT + (size_t)b * CD_ * Q_;
#pragma unroll
  for (int m = 0; m < 4; ++m) {
    int rl = wr * 64 + m * 16 + fq * 4;
#pragma unroll
    for (int n = 0; n < 8; ++n) {
      int cl = wc * 128 + n * 16 + fr;
      f16x4 cv;
#pragma unroll
      for (int r = 0; r < 4; ++r) {
        float v = acc[m][n][r];
        Cb[(size_t)(i0 + rl + r) * PD_ + j0 + cl] = v;
        cv[r] = (_Float16)v;
      }
      *(f16x4*)(Tb + (size_t)(QD_ + j0 + cl) * Q_ + i0 + rl) = cv;
    }
  }
}

// ---------------------------------------------------------------------------
// K5: out1[b][p][c] = sum_q WP[p][q] * candT[c][q]  (rinv pre-folded into WP)
// grid (CD/256, P/128, B)
// ---------------------------------------------------------------------------
__global__ __launch_bounds__(256, 2) void k5_attn(
    const _Float16* __restrict__ WP, const _Float16* __restrict__ candT,
    float* __restrict__ out1) {
  __shared__ alignas(16) _Float16 As[3 * 128 * 32];
  __shared__ alignas(16) _Float16 Bs[3 * 256 * 32];
  SWZ_DECODE(CD_ / 256, P_ / 128)
  int tid = threadIdx.x, w = tid >> 6, l = tid & 63;
  f32x4 acc[4][8];
#pragma unroll
  for (int m = 0; m < 4; ++m)
#pragma unroll
    for (int n = 0; n < 8; ++n) acc[m][n] = (f32x4){0.f, 0.f, 0.f, 0.f};
  gemm_core<Q_ / 32, Q_, Q_>(WP + (size_t)b * P_ * Q_ + (size_t)i0 * Q_,
                             candT + (size_t)b * CD_ * Q_ + (size_t)j0 * Q_, As,
                             Bs, acc, w, l);
  int wr = w >> 1, wc = w & 1, fr = l & 15, fq = l >> 4;
  float* Cb = out1 + (size_t)b * P_ * CD_;
#pragma unroll
  for (int m = 0; m < 4; ++m) {
    int rl = wr * 64 + m * 16 + fq * 4;
#pragma unroll
    for (int n = 0; n < 8; ++n) {
      int cl = wc * 128 + n * 16 + fr;
#pragma unroll
      for (int r = 0; r < 4; ++r)
        Cb[(size_t)(i0 + rl + r) * CD_ + j0 + cl] = acc[m][n][r];
    }
  }
}

// ---------------------------------------------------------------------------
extern "C" void kernel_launch(void* const* d_in, const int* in_sizes, int n_in,
                              void* d_out, int out_size, void* d_ws,
                              size_t ws_size, hipStream_t stream) {
  const float* p = (const float*)d_in[0];
  const float* q = (const float*)d_in[1];
  const int* pmask = (const int*)d_in[2];
  const int* qmask = (const int*)d_in[3];
  const float* W = (const float*)d_in[4];
  float* out = (float*)d_out;

  char* ws = (char*)d_ws;
  size_t off = 0;
  auto alloc = [&](size_t bytes) {
    void* r = ws + off;
    off += (bytes + 255) & ~(size_t)255;
    return r;
  };
  _Float16* q16 = (_Float16*)alloc((size_t)B_ * Q_ * QD_ * 2);
  _Float16* p16 = (_Float16*)alloc((size_t)B_ * P_ * PD_ * 2);
  _Float16* pT = (_Float16*)alloc((size_t)B_ * PD_ * P_ * 2);
  _Float16* candT = (_Float16*)alloc((size_t)B_ * CD_ * Q_ * 2);
  _Float16* W16 = (_Float16*)alloc((size_t)PD_ * QD_ * 2);
  _Float16* qp16 = (_Float16*)alloc((size_t)B_ * Q_ * PD_ * 2);
  float* aff = (float*)alloc((size_t)B_ * P_ * Q_ * 4);
  _Float16* WP = (_Float16*)alloc((size_t)B_ * P_ * Q_ * 2);
  _Float16* WQ = (_Float16*)alloc((size_t)B_ * Q_ * P_ * 2);
  float* rowmax = (float*)alloc((size_t)B_ * P_ * 4);
  float* rowsum = (float*)alloc((size_t)B_ * P_ * 4);
  float* colmax = (float*)alloc((size_t)B_ * Q_ * 4);
  float* colsum = (float*)alloc((size_t)B_ * Q_ * 4);
  float* pmax_part = (float*)alloc((size_t)B_ * 8 * Q_ * 4);
  float* psum_part = (float*)alloc((size_t)B_ * 8 * Q_ * 4);
  float* rpm = (float*)alloc((size_t)B_ * 2 * P_ * 4);
  float* rps = (float*)alloc((size_t)B_ * 2 * P_ * 4);

  float* out1 = out;                          // [B,P,1536]
  float* out2 = out + (size_t)B_ * P_ * CD_;  // [B,Q,768]

  // 1. input preparation (fused convert + transpose; W convert only)
  k_cvt<<<PD_ * QD_ / 8 / 256, 256, 0, stream>>>(W, W16, PD_ * QD_ / 8);
  k_prep<<<dim3(Q_ / 64, QD_ / 64, B_), 256, 0, stream>>>(
      q, q16, candT, Q_, QD_, (size_t)CD_ * Q_);  // candT cols 0..767
  k_prep<<<dim3(P_ / 64, PD_ / 64, B_), 256, 0, stream>>>(
      p, p16, pT, P_, PD_, (size_t)PD_ * P_);
  // 2. K1 projection
  k1_proj<<<dim3(PD_ / 256, Q_ / 128, B_), 256, 0, stream>>>(q16, W16, qp16);
  // 3. K2 affinity + fused row/col stat partials
  k2_aff<<<dim3(Q_ / 256, P_ / 128, B_), 256, 0, stream>>>(
      p16, qp16, pmask, qmask, aff, pmax_part, psum_part, rpm, rps);
  // 4. stat merges
  k_rowmerge<<<B_ * P_ / 256, 256, 0, stream>>>(rpm, rps, rowmax, rowsum);
  k_colmerge<<<dim3(B_, Q_ / 256), 256, 0, stream>>>(pmax_part, psum_part,
                                                     colmax, colsum);
  // 5. fused weights (one aff read -> WP + WQ)
  k_w<<<dim3(P_ / 64, Q_ / 64, B_), 256, 0, stream>>>(
      aff, pmask, qmask, rowmax, rowsum, colmax, colsum, WP, WQ);
  // 6. K4 -> out2 + candT upper half
  k4_attn<<<dim3(PD_ / 256, Q_ / 128, B_), 256, 0, stream>>>(WQ, pT, out2,
                                                             candT);
  // 7. K5 -> out1
  k5_attn<<<dim3(CD_ / 256, P_ / 128, B_), 256, 0, stream>>>(WP, candT, out1);
}

// Round 6
// 168.206 us; speedup vs baseline: 1.1462x; 1.1462x over previous
//
#include <hip/hip_runtime.h>
#include <math.h>

// Problem constants
constexpr int B_  = 16;
constexpr int P_  = 1024;
constexpr int Q_  = 512;
constexpr int PD_ = 768;   // p_dim
constexpr int QD_ = 768;   // q_dim
constexpr int CD_ = 1536;  // q_dim + p_dim

#define HUGE_NEG (-1e8f)

typedef __attribute__((ext_vector_type(8))) _Float16 f16x8;
typedef __attribute__((ext_vector_type(4))) _Float16 f16x4;
typedef __attribute__((ext_vector_type(4))) float f32x4;

// async global->LDS DMA, 16B/lane: HW writes lds_base + lane*16 (wave-linear).
__device__ __forceinline__ void dma16(const void* g, void* l) {
  __builtin_amdgcn_global_load_lds((__attribute__((address_space(1))) void*)g,
                                   (__attribute__((address_space(3))) void*)l,
                                   16, 0, 0);
}

// ---------------------------------------------------------------------------
// fp32 -> fp16 convert, 8 elems/thread (W only).
// ---------------------------------------------------------------------------
__global__ __launch_bounds__(256) void k_cvt(const float* __restrict__ src,
                                             _Float16* __restrict__ dst, int n8) {
  int i = blockIdx.x * 256 + threadIdx.x;
  if (i >= n8) return;
  float4 a = ((const float4*)src)[2 * i];
  float4 b = ((const float4*)src)[2 * i + 1];
  f16x8 o = {(_Float16)a.x, (_Float16)a.y, (_Float16)a.z, (_Float16)a.w,
             (_Float16)b.x, (_Float16)b.y, (_Float16)b.z, (_Float16)b.w};
  ((f16x8*)dst)[i] = o;
}

// ---------------------------------------------------------------------------
// Fused convert+transpose: read fp32 src[b][R][C] once ->
//   dst16[b][R][C] fp16 (row-major) AND dstT[b][C][R] fp16 (transposed).
// 64x64 tiles. grid = (R/64, C/64, B)
// ---------------------------------------------------------------------------
__global__ __launch_bounds__(256) void k_prep(const float* __restrict__ src,
                                              _Float16* __restrict__ dst16,
                                              _Float16* __restrict__ dstT,
                                              int R, int C, size_t tBatch) {
  __shared__ _Float16 T[64][72];
  int r0 = blockIdx.x * 64, c0 = blockIdx.y * 64, b = blockIdx.z;
  const float* S = src + (size_t)b * R * C;
  _Float16* D16 = dst16 + (size_t)b * R * C;
  int tid = threadIdx.x;
  int rr = tid >> 4;
  int cc = (tid & 15) * 4;
#pragma unroll
  for (int k = 0; k < 4; ++k) {
    int r = rr + k * 16;
    float4 v = *(const float4*)(S + (size_t)(r0 + r) * C + c0 + cc);
    f16x4 h = {(_Float16)v.x, (_Float16)v.y, (_Float16)v.z, (_Float16)v.w};
    *(f16x4*)(D16 + (size_t)(r0 + r) * C + c0 + cc) = h;
    T[cc + 0][r] = h[0];
    T[cc + 1][r] = h[1];
    T[cc + 2][r] = h[2];
    T[cc + 3][r] = h[3];
  }
  __syncthreads();
  int cr = tid >> 2;
  int rc = (tid & 3) * 16;
  _Float16* D = dstT + (size_t)b * tBatch + (size_t)(c0 + cr) * R + r0;
  *(f16x8*)(D + rc) = *(f16x8*)&T[cr][rc];
  *(f16x8*)(D + rc + 8) = *(f16x8*)&T[cr][rc + 8];
}

// ---------------------------------------------------------------------------
// Merge 4 row-stat partials. grid = B*P/256.
// ---------------------------------------------------------------------------
__global__ __launch_bounds__(256) void k_rowmerge(
    const float* __restrict__ rpm, const float* __restrict__ rps,
    float* __restrict__ rowmax, float* __restrict__ rowsum) {
  int idx = blockIdx.x * 256 + threadIdx.x;  // b*P + p
  int b = idx >> 10, p = idx & 1023;
  float m = -INFINITY;
#pragma unroll
  for (int z = 0; z < 4; ++z) m = fmaxf(m, rpm[(b * 4 + z) * P_ + p]);
  float s = 0.f;
#pragma unroll
  for (int z = 0; z < 4; ++z)
    s += rps[(b * 4 + z) * P_ + p] * __expf(rpm[(b * 4 + z) * P_ + p] - m);
  rowmax[idx] = m;
  rowsum[idx] = s;
}

// ---------------------------------------------------------------------------
// Merge 8 column-stat partials. grid = (B, Q/256), block = 256.
// ---------------------------------------------------------------------------
__global__ __launch_bounds__(256) void k_colmerge(
    const float* __restrict__ pmax_part, const float* __restrict__ psum_part,
    float* __restrict__ colmax, float* __restrict__ colsum) {
  int b = blockIdx.x;
  int q = blockIdx.y * 256 + threadIdx.x;
  float m = -INFINITY;
#pragma unroll
  for (int z = 0; z < 8; ++z) m = fmaxf(m, pmax_part[(b * 8 + z) * Q_ + q]);
  float s = 0.f;
#pragma unroll
  for (int z = 0; z < 8; ++z)
    s += psum_part[(b * 8 + z) * Q_ + q] *
         __expf(pmax_part[(b * 8 + z) * Q_ + q] - m);
  colmax[b * Q_ + q] = m;
  colsum[b * Q_ + q] = s;
}

// ---------------------------------------------------------------------------
// Fused weights kernel: ONE read of aff produces
//   WP[b][p][q] = fp16(exp((qmask?-H:v)-rowmax[p]) / rowsum[p])   (row-major)
//   WQ[b][q][p] = fp16(exp((pmask?-H:v)-colmax[q]) / colsum[q])   (transposed)
// grid = (P/64, Q/64, B)
// ---------------------------------------------------------------------------
__global__ __launch_bounds__(256) void k_w(
    const float* __restrict__ aff, const int* __restrict__ pmask,
    const int* __restrict__ qmask, const float* __restrict__ rowmax,
    const float* __restrict__ rowsum, const float* __restrict__ colmax,
    const float* __restrict__ colsum, _Float16* __restrict__ WP,
    _Float16* __restrict__ WQ) {
  __shared__ _Float16 T[64][72];
  __shared__ float rmx[64], rin[64], cmx[64], cin[64];
  int p0 = blockIdx.x * 64, q0 = blockIdx.y * 64, b = blockIdx.z;
  int tid = threadIdx.x;
  if (tid < 64) {
    rmx[tid] = rowmax[b * P_ + p0 + tid];
    rin[tid] = 1.0f / rowsum[b * P_ + p0 + tid];
  } else if (tid < 128) {
    int t = tid - 64;
    cmx[t] = colmax[b * Q_ + q0 + t];
    cin[t] = 1.0f / colsum[b * Q_ + q0 + t];
  }
  __syncthreads();
  const float* A = aff + (size_t)b * P_ * Q_;
  const int* pm = pmask + b * P_;
  int rr = tid >> 4;
  int cc = (tid & 15) * 4;
  int4 qm4 = *(const int4*)(qmask + b * Q_ + q0 + cc);
  int qm[4] = {qm4.x, qm4.y, qm4.z, qm4.w};
#pragma unroll
  for (int k = 0; k < 4; ++k) {
    int r = rr + k * 16;
    int msk = pm[p0 + r];
    float4 v = *(const float4*)(A + (size_t)(p0 + r) * Q_ + q0 + cc);
    float vv[4] = {v.x, v.y, v.z, v.w};
    f16x4 wp;
#pragma unroll
    for (int j = 0; j < 4; ++j) {
      wp[j] = (_Float16)(__expf((qm[j] ? HUGE_NEG : vv[j]) - rmx[r]) * rin[r]);
      T[cc + j][r] =
          (_Float16)(__expf((msk ? HUGE_NEG : vv[j]) - cmx[cc + j]) * cin[cc + j]);
    }
    *(f16x4*)(WP + ((size_t)b * P_ + p0 + r) * Q_ + q0 + cc) = wp;
  }
  __syncthreads();
  int cr = tid >> 2;
  int rc = (tid & 3) * 16;
  _Float16* D = WQ + ((size_t)b * Q_ + q0 + cr) * P_ + p0;
  *(f16x8*)(D + rc) = *(f16x8*)&T[cr][rc];
  *(f16x8*)(D + rc + 8) = *(f16x8*)&T[cr][rc + 8];
}

// ---------------------------------------------------------------------------
// GEMM core (r4-proven): 128x128 tile, 4 waves, BK=32, 3-buffer 2-deep
// prefetch, counted vmcnt (8/4/0), raw barriers, chunk-XOR LDS swizzle.
// C = A(rows i, k-contig, LDA) x B(rows j, k-contig, LDB)^T, fp32 acc.
// ---------------------------------------------------------------------------
template <int NT, int LDA, int LDB>
__device__ __forceinline__ void gemm_core(const _Float16* __restrict__ Ab,
                                          const _Float16* __restrict__ Bb,
                                          _Float16* As, _Float16* Bs,
                                          f32x4 (&acc)[4][4], int w, int l) {
  constexpr int TSZ = 128 * 32;
  int rA = w * 32 + (l >> 2);                       // staged local row
  int sA = ((l & 3) ^ ((rA >> 1) & 3)) * 8;         // swizzled src chunk
  int fr = l & 15;
  int fsw = (((l >> 4) ^ ((fr >> 1) & 3))) * 8;     // swizzled read offset
  int wr = w >> 1, wc = w & 1;

  auto stage = [&](int buf, int t) {
    const _Float16* ga = Ab + (size_t)rA * LDA + t * 32 + sA;
    const _Float16* gb = Bb + (size_t)rA * LDB + t * 32 + sA;
    _Float16* la = As + buf * TSZ + (w * 32) * 32;
    _Float16* lb = Bs + buf * TSZ + (w * 32) * 32;
    dma16(ga, la);
    dma16(ga + 16 * LDA, la + 16 * 32);
    dma16(gb, lb);
    dma16(gb + 16 * LDB, lb + 16 * 32);
  };
  auto compute = [&](int buf) {
    const _Float16* A0 = As + buf * TSZ;
    const _Float16* B0 = Bs + buf * TSZ;
    f16x8 a[4];
#pragma unroll
    for (int m = 0; m < 4; ++m)
      a[m] = *(const f16x8*)(A0 + (wr * 64 + m * 16 + fr) * 32 + fsw);
#pragma unroll
    for (int n = 0; n < 4; ++n) {
      f16x8 bn = *(const f16x8*)(B0 + (wc * 64 + n * 16 + fr) * 32 + fsw);
#pragma unroll
      for (int m = 0; m < 4; ++m)
        acc[m][n] =
            __builtin_amdgcn_mfma_f32_16x16x32_f16(a[m], bn, acc[m][n], 0, 0, 0);
    }
  };

  stage(0, 0);
  stage(1, 1);
  int b0 = 0, b1 = 1, b2 = 2;
#pragma unroll 3
  for (int t = 0; t < NT - 2; ++t) {
    stage(b2, t + 2);
    asm volatile("s_waitcnt vmcnt(8)" ::: "memory");
    __builtin_amdgcn_s_barrier();
    __builtin_amdgcn_sched_barrier(0);
    compute(b0);
    __builtin_amdgcn_s_barrier();
    int tmp = b0; b0 = b1; b1 = b2; b2 = tmp;
  }
  asm volatile("s_waitcnt vmcnt(4)" ::: "memory");
  __builtin_amdgcn_s_barrier();
  __builtin_amdgcn_sched_barrier(0);
  compute(b0);
  __builtin_amdgcn_s_barrier();
  asm volatile("s_waitcnt vmcnt(0)" ::: "memory");
  __builtin_amdgcn_s_barrier();
  __builtin_amdgcn_sched_barrier(0);
  compute(b1);
}

// bijective XCD swizzle (nwg % 8 == 0)
#define SWZ_DECODE(GX, GY)                                          \
  int lin = blockIdx.x + (GX) * (blockIdx.y + (GY) * blockIdx.z);   \
  constexpr int NWG = (GX) * (GY) * B_;                             \
  int w8 = (lin & 7) * (NWG / 8) + (lin >> 3);                      \
  int j0 = (w8 % (GX)) * 128;                                       \
  int t_ = w8 / (GX);                                               \
  int i0 = (t_ % (GY)) * 128;                                       \
  int b = t_ / (GY);

// ---------------------------------------------------------------------------
// K1: qp[b][q][pd] = sum_d q16[q][d] * W16[pd][d]. grid (PD/128, Q/128, B)
// ---------------------------------------------------------------------------
__global__ __launch_bounds__(256) void k1_proj(const _Float16* __restrict__ q16,
                                               const _Float16* __restrict__ W16,
                                               _Float16* __restrict__ qp) {
  __shared__ alignas(16) _Float16 As[3 * 128 * 32];
  __shared__ alignas(16) _Float16 Bs[3 * 128 * 32];
  SWZ_DECODE(PD_ / 128, Q_ / 128)
  int tid = threadIdx.x, w = tid >> 6, l = tid & 63;
  f32x4 acc[4][4];
#pragma unroll
  for (int m = 0; m < 4; ++m)
#pragma unroll
    for (int n = 0; n < 4; ++n) acc[m][n] = (f32x4){0.f, 0.f, 0.f, 0.f};
  gemm_core<QD_ / 32, QD_, QD_>(q16 + (size_t)b * Q_ * QD_ + (size_t)i0 * QD_,
                                W16 + (size_t)j0 * QD_, As, Bs, acc, w, l);
  int wr = w >> 1, wc = w & 1, fr = l & 15, fq = l >> 4;
  _Float16* O = qp + (size_t)b * Q_ * PD_;
#pragma unroll
  for (int m = 0; m < 4; ++m) {
    int rl = wr * 64 + m * 16 + fq * 4;
#pragma unroll
    for (int n = 0; n < 4; ++n) {
      int cl = wc * 64 + n * 16 + fr;
#pragma unroll
      for (int r = 0; r < 4; ++r)
        O[(size_t)(i0 + rl + r) * PD_ + j0 + cl] = (_Float16)acc[m][n][r];
    }
  }
}

// ---------------------------------------------------------------------------
// K2: aff[b][p][q] = sum_d p16[p][d] * qp[q][d]. grid (Q/128, P/128, B)
// Epilogue: fp32 aff write + BOTH softmax-stat partials from the fp32 accs:
//   col partials (over 128 p-rows, pmask) -> pmax/psum_part[z = i0/128]
//   row partials (over 128 q-cols, qmask) -> rpm/rps[zj = j0/128]
// ---------------------------------------------------------------------------
__global__ __launch_bounds__(256) void k2_aff(
    const _Float16* __restrict__ p16, const _Float16* __restrict__ qp,
    const int* __restrict__ pmask, const int* __restrict__ qmask,
    float* __restrict__ aff, float* __restrict__ pmax_part,
    float* __restrict__ psum_part, float* __restrict__ rpm,
    float* __restrict__ rps) {
  __shared__ alignas(16) _Float16 As[3 * 128 * 32];
  __shared__ alignas(16) _Float16 Bs[3 * 128 * 32];
  SWZ_DECODE(Q_ / 128, P_ / 128)
  int tid = threadIdx.x, w = tid >> 6, l = tid & 63;
  f32x4 acc[4][4];
#pragma unroll
  for (int m = 0; m < 4; ++m)
#pragma unroll
    for (int n = 0; n < 4; ++n) acc[m][n] = (f32x4){0.f, 0.f, 0.f, 0.f};
  gemm_core<PD_ / 32, PD_, PD_>(p16 + (size_t)b * P_ * PD_ + (size_t)i0 * PD_,
                                qp + (size_t)b * Q_ * PD_ + (size_t)j0 * PD_,
                                As, Bs, acc, w, l);
  int wr = w >> 1, wc = w & 1, fr = l & 15, fq = l >> 4;
  float* Cb = aff + (size_t)b * P_ * Q_;
#pragma unroll
  for (int m = 0; m < 4; ++m) {
    int rl = wr * 64 + m * 16 + fq * 4;
#pragma unroll
    for (int n = 0; n < 4; ++n) {
      int cl = wc * 64 + n * 16 + fr;
#pragma unroll
      for (int r = 0; r < 4; ++r)
        Cb[(size_t)(i0 + rl + r) * Q_ + j0 + cl] = acc[m][n][r];
    }
  }
  // ---- fused softmax stat partials ----
  const int* pmb = pmask + b * P_ + i0;
  unsigned pmbits = 0;
#pragma unroll
  for (int m = 0; m < 4; ++m)
#pragma unroll
    for (int r = 0; r < 4; ++r)
      pmbits |= (pmb[wr * 64 + m * 16 + fq * 4 + r] ? 1u : 0u) << (m * 4 + r);
  int qmv[4];
  {
    const int* qmb = qmask + b * Q_ + j0 + wc * 64 + fr;
#pragma unroll
    for (int n = 0; n < 4; ++n) qmv[n] = qmb[n * 16];
  }
  __syncthreads();  // all GEMM LDS reads done before scratch reuse
  float* scr = (float*)As;  // 4KB scratch
  float* cm_ = scr;         // [2][128]
  float* cs_ = scr + 256;
  float* rm_ = scr + 512;   // [2][128]
  float* rs_ = scr + 768;

  // column partials: reduce over 128 rows (m,r in reg; fq lanes; wr via LDS)
#pragma unroll
  for (int n = 0; n < 4; ++n) {
    float ml = -1e30f;
#pragma unroll
    for (int m = 0; m < 4; ++m)
#pragma unroll
      for (int r = 0; r < 4; ++r) {
        float v = ((pmbits >> (m * 4 + r)) & 1) ? HUGE_NEG : acc[m][n][r];
        ml = fmaxf(ml, v);
      }
    float sl = 0.f;
#pragma unroll
    for (int m = 0; m < 4; ++m)
#pragma unroll
      for (int r = 0; r < 4; ++r) {
        float v = ((pmbits >> (m * 4 + r)) & 1) ? HUGE_NEG : acc[m][n][r];
        sl += __expf(v - ml);
      }
#pragma unroll
    for (int off = 16; off <= 32; off <<= 1) {
      float om = __shfl_xor(ml, off);
      float os = __shfl_xor(sl, off);
      float nm = fmaxf(ml, om);
      sl = sl * __expf(ml - nm) + os * __expf(om - nm);
      ml = nm;
    }
    if (fq == 0) {
      int col = wc * 64 + n * 16 + fr;
      cm_[wr * 128 + col] = ml;
      cs_[wr * 128 + col] = sl;
    }
  }
  // row partials: reduce over 128 cols (n in reg; fr lanes; wc via LDS)
#pragma unroll
  for (int m = 0; m < 4; ++m)
#pragma unroll
    for (int r = 0; r < 4; ++r) {
      float ml = -1e30f;
#pragma unroll
      for (int n = 0; n < 4; ++n) {
        float v = qmv[n] ? HUGE_NEG : acc[m][n][r];
        ml = fmaxf(ml, v);
      }
      float sl = 0.f;
#pragma unroll
      for (int n = 0; n < 4; ++n) {
        float v = qmv[n] ? HUGE_NEG : acc[m][n][r];
        sl += __expf(v - ml);
      }
#pragma unroll
      for (int off = 1; off <= 8; off <<= 1) {
        float om = __shfl_xor(ml, off);
        float os = __shfl_xor(sl, off);
        float nm = fmaxf(ml, om);
        sl = sl * __expf(ml - nm) + os * __expf(om - nm);
        ml = nm;
      }
      if (fr == 0) {
        int row = wr * 64 + m * 16 + fq * 4 + r;
        rm_[wc * 128 + row] = ml;
        rs_[wc * 128 + row] = sl;
      }
    }
  __syncthreads();
  if (tid < 128) {
    float m0 = cm_[tid], m1 = cm_[128 + tid];
    float s0 = cs_[tid], s1 = cs_[128 + tid];
    float nm = fmaxf(m0, m1);
    float ns = s0 * __expf(m0 - nm) + s1 * __expf(m1 - nm);
    int z = i0 >> 7;
    pmax_part[(b * 8 + z) * Q_ + j0 + tid] = nm;
    psum_part[(b * 8 + z) * Q_ + j0 + tid] = ns;
  } else {
    int t = tid - 128;
    if (t < 128) {
      float m0 = rm_[t], m1 = rm_[128 + t];
      float s0 = rs_[t], s1 = rs_[128 + t];
      float nm = fmaxf(m0, m1);
      float ns = s0 * __expf(m0 - nm) + s1 * __expf(m1 - nm);
      int zj = j0 >> 7;
      rpm[(b * 4 + zj) * P_ + i0 + t] = nm;
      rps[(b * 4 + zj) * P_ + i0 + t] = ns;
    }
  }
}

// ---------------------------------------------------------------------------
// K4: out2[b][q][d] = sum_p WQ[q][p] * pT[d][p]  (cinv pre-folded into WQ)
// Also writes candT[b][768+d][q] fp16. grid (PD/128, Q/128, B)
// ---------------------------------------------------------------------------
__global__ __launch_bounds__(256) void k4_attn(const _Float16* __restrict__ WQ,
                                               const _Float16* __restrict__ pT,
                                               float* __restrict__ out2,
                                               _Float16* __restrict__ candT) {
  __shared__ alignas(16) _Float16 As[3 * 128 * 32];
  __shared__ alignas(16) _Float16 Bs[3 * 128 * 32];
  SWZ_DECODE(PD_ / 128, Q_ / 128)
  int tid = threadIdx.x, w = tid >> 6, l = tid & 63;
  f32x4 acc[4][4];
#pragma unroll
  for (int m = 0; m < 4; ++m)
#pragma unroll
    for (int n = 0; n < 4; ++n) acc[m][n] = (f32x4){0.f, 0.f, 0.f, 0.f};
  gemm_core<P_ / 32, P_, P_>(WQ + (size_t)b * Q_ * P_ + (size_t)i0 * P_,
                             pT + (size_t)b * PD_ * P_ + (size_t)j0 * P_, As,
                             Bs, acc, w, l);
  int wr = w >> 1, wc = w & 1, fr = l & 15, fq = l >> 4;
  float* Cb = out2 + (size_t)b * Q_ * PD_;
  _Float16* Tb = candT + (size_t)b * CD_ * Q_;
#pragma unroll
  for (int m = 0; m < 4; ++m) {
    int rl = wr * 64 + m * 16 + fq * 4;
#pragma unroll
    for (int n = 0; n < 4; ++n) {
      int cl = wc * 64 + n * 16 + fr;
      f16x4 cv;
#pragma unroll
      for (int r = 0; r < 4; ++r) {
        float v = acc[m][n][r];
        Cb[(size_t)(i0 + rl + r) * PD_ + j0 + cl] = v;
        cv[r] = (_Float16)v;
      }
      *(f16x4*)(Tb + (size_t)(QD_ + j0 + cl) * Q_ + i0 + rl) = cv;
    }
  }
}

// ---------------------------------------------------------------------------
// K5: out1[b][p][c] = sum_q WP[p][q] * candT[c][q]  (rinv pre-folded into WP)
// grid (CD/128, P/128, B)
// ---------------------------------------------------------------------------
__global__ __launch_bounds__(256) void k5_attn(const _Float16* __restrict__ WP,
                                               const _Float16* __restrict__ candT,
                                               float* __restrict__ out1) {
  __shared__ alignas(16) _Float16 As[3 * 128 * 32];
  __shared__ alignas(16) _Float16 Bs[3 * 128 * 32];
  SWZ_DECODE(CD_ / 128, P_ / 128)
  int tid = threadIdx.x, w = tid >> 6, l = tid & 63;
  f32x4 acc[4][4];
#pragma unroll
  for (int m = 0; m < 4; ++m)
#pragma unroll
    for (int n = 0; n < 4; ++n) acc[m][n] = (f32x4){0.f, 0.f, 0.f, 0.f};
  gemm_core<Q_ / 32, Q_, Q_>(WP + (size_t)b * P_ * Q_ + (size_t)i0 * Q_,
                             candT + (size_t)b * CD_ * Q_ + (size_t)j0 * Q_, As,
                             Bs, acc, w, l);
  int wr = w >> 1, wc = w & 1, fr = l & 15, fq = l >> 4;
  float* Cb = out1 + (size_t)b * P_ * CD_;
#pragma unroll
  for (int m = 0; m < 4; ++m) {
    int rl = wr * 64 + m * 16 + fq * 4;
#pragma unroll
    for (int n = 0; n < 4; ++n) {
      int cl = wc * 64 + n * 16 + fr;
#pragma unroll
      for (int r = 0; r < 4; ++r)
        Cb[(size_t)(i0 + rl + r) * CD_ + j0 + cl] = acc[m][n][r];
    }
  }
}

// ---------------------------------------------------------------------------
extern "C" void kernel_launch(void* const* d_in, const int* in_sizes, int n_in,
                              void* d_out, int out_size, void* d_ws,
                              size_t ws_size, hipStream_t stream) {
  const float* p = (const float*)d_in[0];
  const float* q = (const float*)d_in[1];
  const int* pmask = (const int*)d_in[2];
  const int* qmask = (const int*)d_in[3];
  const float* W = (const float*)d_in[4];
  float* out = (float*)d_out;

  char* ws = (char*)d_ws;
  size_t off = 0;
  auto alloc = [&](size_t bytes) {
    void* r = ws + off;
    off += (bytes + 255) & ~(size_t)255;
    return r;
  };
  _Float16* q16 = (_Float16*)alloc((size_t)B_ * Q_ * QD_ * 2);
  _Float16* p16 = (_Float16*)alloc((size_t)B_ * P_ * PD_ * 2);
  _Float16* pT = (_Float16*)alloc((size_t)B_ * PD_ * P_ * 2);
  _Float16* candT = (_Float16*)alloc((size_t)B_ * CD_ * Q_ * 2);
  _Float16* W16 = (_Float16*)alloc((size_t)PD_ * QD_ * 2);
  _Float16* qp16 = (_Float16*)alloc((size_t)B_ * Q_ * PD_ * 2);
  float* aff = (float*)alloc((size_t)B_ * P_ * Q_ * 4);
  _Float16* WP = (_Float16*)alloc((size_t)B_ * P_ * Q_ * 2);
  _Float16* WQ = (_Float16*)alloc((size_t)B_ * Q_ * P_ * 2);
  float* rowmax = (float*)alloc((size_t)B_ * P_ * 4);
  float* rowsum = (float*)alloc((size_t)B_ * P_ * 4);
  float* colmax = (float*)alloc((size_t)B_ * Q_ * 4);
  float* colsum = (float*)alloc((size_t)B_ * Q_ * 4);
  float* pmax_part = (float*)alloc((size_t)B_ * 8 * Q_ * 4);
  float* psum_part = (float*)alloc((size_t)B_ * 8 * Q_ * 4);
  float* rpm = (float*)alloc((size_t)B_ * 4 * P_ * 4);
  float* rps = (float*)alloc((size_t)B_ * 4 * P_ * 4);

  float* out1 = out;                          // [B,P,1536]
  float* out2 = out + (size_t)B_ * P_ * CD_;  // [B,Q,768]

  // 1. input preparation (fused convert + transpose; W convert only)
  k_cvt<<<PD_ * QD_ / 8 / 256, 256, 0, stream>>>(W, W16, PD_ * QD_ / 8);
  k_prep<<<dim3(Q_ / 64, QD_ / 64, B_), 256, 0, stream>>>(
      q, q16, candT, Q_, QD_, (size_t)CD_ * Q_);  // candT cols 0..767
  k_prep<<<dim3(P_ / 64, PD_ / 64, B_), 256, 0, stream>>>(
      p, p16, pT, P_, PD_, (size_t)PD_ * P_);
  // 2. K1 projection
  k1_proj<<<dim3(PD_ / 128, Q_ / 128, B_), 256, 0, stream>>>(q16, W16, qp16);
  // 3. K2 affinity + fused row/col stat partials
  k2_aff<<<dim3(Q_ / 128, P_ / 128, B_), 256, 0, stream>>>(
      p16, qp16, pmask, qmask, aff, pmax_part, psum_part, rpm, rps);
  // 4. stat merges
  k_rowmerge<<<B_ * P_ / 256, 256, 0, stream>>>(rpm, rps, rowmax, rowsum);
  k_colmerge<<<dim3(B_, Q_ / 256), 256, 0, stream>>>(pmax_part, psum_part,
                                                     colmax, colsum);
  // 5. fused weights (one aff read -> WP + WQ)
  k_w<<<dim3(P_ / 64, Q_ / 64, B_), 256, 0, stream>>>(
      aff, pmask, qmask, rowmax, rowsum, colmax, colsum, WP, WQ);
  // 6. K4 -> out2 + candT upper half
  k4_attn<<<dim3(PD_ / 128, Q_ / 128, B_), 256, 0, stream>>>(WQ, pT, out2,
                                                             candT);
  // 7. K5 -> out1
  k5_attn<<<dim3(CD_ / 128, P_ / 128, B_), 256, 0, stream>>>(WP, candT, out1);
}

// Round 8
// 167.991 us; speedup vs baseline: 1.1477x; 1.0013x over previous
//
#include <hip/hip_runtime.h>
#include <math.h>

// Problem constants
constexpr int B_  = 16;
constexpr int P_  = 1024;
constexpr int Q_  = 512;
constexpr int PD_ = 768;   // p_dim
constexpr int QD_ = 768;   // q_dim
constexpr int CD_ = 1536;  // q_dim + p_dim

#define HUGE_NEG (-1e8f)

typedef __attribute__((ext_vector_type(8))) _Float16 f16x8;
typedef __attribute__((ext_vector_type(4))) _Float16 f16x4;
typedef __attribute__((ext_vector_type(4))) float f32x4;

// async global->LDS DMA, 16B/lane: HW writes lds_base + lane*16 (wave-linear).
__device__ __forceinline__ void dma16(const void* g, void* l) {
  __builtin_amdgcn_global_load_lds((__attribute__((address_space(1))) void*)g,
                                   (__attribute__((address_space(3))) void*)l,
                                   16, 0, 0);
}

// ---------------------------------------------------------------------------
// fp32 -> fp16 convert, 8 elems/thread (W only).
// ---------------------------------------------------------------------------
__global__ __launch_bounds__(256) void k_cvt(const float* __restrict__ src,
                                             _Float16* __restrict__ dst, int n8) {
  int i = blockIdx.x * 256 + threadIdx.x;
  if (i >= n8) return;
  float4 a = ((const float4*)src)[2 * i];
  float4 b = ((const float4*)src)[2 * i + 1];
  f16x8 o = {(_Float16)a.x, (_Float16)a.y, (_Float16)a.z, (_Float16)a.w,
             (_Float16)b.x, (_Float16)b.y, (_Float16)b.z, (_Float16)b.w};
  ((f16x8*)dst)[i] = o;
}

// ---------------------------------------------------------------------------
// Fused convert+transpose: read fp32 src[b][R][C] once ->
//   dst16[b][R][C] fp16 (row-major) AND dstT[b][C][R] fp16 (transposed).
// 64x64 tiles. grid = (R/64, C/64, B)
// ---------------------------------------------------------------------------
__global__ __launch_bounds__(256) void k_prep(const float* __restrict__ src,
                                              _Float16* __restrict__ dst16,
                                              _Float16* __restrict__ dstT,
                                              int R, int C, size_t tBatch) {
  __shared__ _Float16 T[64][72];
  int r0 = blockIdx.x * 64, c0 = blockIdx.y * 64, b = blockIdx.z;
  const float* S = src + (size_t)b * R * C;
  _Float16* D16 = dst16 + (size_t)b * R * C;
  int tid = threadIdx.x;
  int rr = tid >> 4;
  int cc = (tid & 15) * 4;
#pragma unroll
  for (int k = 0; k < 4; ++k) {
    int r = rr + k * 16;
    float4 v = *(const float4*)(S + (size_t)(r0 + r) * C + c0 + cc);
    f16x4 h = {(_Float16)v.x, (_Float16)v.y, (_Float16)v.z, (_Float16)v.w};
    *(f16x4*)(D16 + (size_t)(r0 + r) * C + c0 + cc) = h;
    T[cc + 0][r] = h[0];
    T[cc + 1][r] = h[1];
    T[cc + 2][r] = h[2];
    T[cc + 3][r] = h[3];
  }
  __syncthreads();
  int cr = tid >> 2;
  int rc = (tid & 3) * 16;
  _Float16* D = dstT + (size_t)b * tBatch + (size_t)(c0 + cr) * R + r0;
  *(f16x8*)(D + rc) = *(f16x8*)&T[cr][rc];
  *(f16x8*)(D + rc + 8) = *(f16x8*)&T[cr][rc + 8];
}

// ---------------------------------------------------------------------------
// Fused weights kernel: merges stat partials in-block (4 col + 4 row), then
// ONE aff read ->
//   WP[b][p][q] = fp16(exp((qmask?-H:v)-rowmax[p]) / rowsum[p])   (row-major)
//   WQ[b][q][p] = fp16(exp((pmask?-H:v)-colmax[q]) / colsum[q])   (transposed)
// grid = (P/64, Q/64, B)
// ---------------------------------------------------------------------------
__global__ __launch_bounds__(256) void k_w(
    const float* __restrict__ aff, const int* __restrict__ pmask,
    const int* __restrict__ qmask, const float* __restrict__ rpm,
    const float* __restrict__ rps, const float* __restrict__ pmax_part,
    const float* __restrict__ psum_part, _Float16* __restrict__ WP,
    _Float16* __restrict__ WQ) {
  __shared__ _Float16 T[64][72];
  __shared__ float rmx[64], rin[64], cmx[64], cin[64];
  int p0 = blockIdx.x * 64, q0 = blockIdx.y * 64, b = blockIdx.z;
  int tid = threadIdx.x;
  if (tid < 64) {
    int pp = p0 + tid;
    float m = -INFINITY;
#pragma unroll
    for (int z = 0; z < 4; ++z) m = fmaxf(m, rpm[(b * 4 + z) * P_ + pp]);
    float s = 0.f;
#pragma unroll
    for (int z = 0; z < 4; ++z)
      s += rps[(b * 4 + z) * P_ + pp] * __expf(rpm[(b * 4 + z) * P_ + pp] - m);
    rmx[tid] = m;
    rin[tid] = 1.0f / s;
  } else if (tid < 128) {
    int t = tid - 64;
    int qq = q0 + t;
    float m = -INFINITY;
#pragma unroll
    for (int z = 0; z < 4; ++z) m = fmaxf(m, pmax_part[(b * 4 + z) * Q_ + qq]);
    float s = 0.f;
#pragma unroll
    for (int z = 0; z < 4; ++z)
      s += psum_part[(b * 4 + z) * Q_ + qq] *
           __expf(pmax_part[(b * 4 + z) * Q_ + qq] - m);
    cmx[t] = m;
    cin[t] = 1.0f / s;
  }
  __syncthreads();
  const float* A = aff + (size_t)b * P_ * Q_;
  const int* pm = pmask + b * P_;
  int rr = tid >> 4;
  int cc = (tid & 15) * 4;
  int4 qm4 = *(const int4*)(qmask + b * Q_ + q0 + cc);
  int qm[4] = {qm4.x, qm4.y, qm4.z, qm4.w};
#pragma unroll
  for (int k = 0; k < 4; ++k) {
    int r = rr + k * 16;
    int msk = pm[p0 + r];
    float4 v = *(const float4*)(A + (size_t)(p0 + r) * Q_ + q0 + cc);
    float vv[4] = {v.x, v.y, v.z, v.w};
    f16x4 wp;
#pragma unroll
    for (int j = 0; j < 4; ++j) {
      wp[j] = (_Float16)(__expf((qm[j] ? HUGE_NEG : vv[j]) - rmx[r]) * rin[r]);
      T[cc + j][r] =
          (_Float16)(__expf((msk ? HUGE_NEG : vv[j]) - cmx[cc + j]) * cin[cc + j]);
    }
    *(f16x4*)(WP + ((size_t)b * P_ + p0 + r) * Q_ + q0 + cc) = wp;
  }
  __syncthreads();
  int cr = tid >> 2;
  int rc = (tid & 3) * 16;
  _Float16* D = WQ + ((size_t)b * Q_ + q0 + cr) * P_ + p0;
  *(f16x8*)(D + rc) = *(f16x8*)&T[cr][rc];
  *(f16x8*)(D + rc + 8) = *(f16x8*)&T[cr][rc + 8];
}

// ---------------------------------------------------------------------------
// GEMM core 8-wave: 256x128 tile, 8 waves (4Mx2N, 64x64 each), BK=32,
// 3-buffer 2-deep prefetch, counted vmcnt (6/3/0), raw barriers,
// chunk-XOR LDS swizzle (same proven 16x16x32 MFMA + fragment paths).
// C = A(rows i, k-contig, LDA) x B(rows j, k-contig, LDB)^T, fp32 acc.
// Per K-step: A stage 2 dma/lane (rows w*32+(l>>2), +16), B stage 1 dma/lane
// (rows w*16+(l>>2)). Stage swizzle key (l>>3)&3 valid for both (row-band
// offsets === 0 mod 4 rows); read key (fr>>1)&3 likewise.
// ---------------------------------------------------------------------------
template <int NT, int LDA, int LDB>
__device__ __forceinline__ void gemm_core(const _Float16* __restrict__ Ab,
                                          const _Float16* __restrict__ Bb,
                                          _Float16* As, _Float16* Bs,
                                          f32x4 (&acc)[4][4], int w, int l) {
  constexpr int ASZ = 256 * 32, BSZ = 128 * 32;
  int rA = w * 32 + (l >> 2);
  int rB = w * 16 + (l >> 2);
  int sk = ((l & 3) ^ ((l >> 3) & 3)) * 8;          // staging src chunk swizzle
  int fr = l & 15;
  int fsw = (((l >> 4) ^ ((fr >> 1) & 3))) * 8;     // read-side swizzle
  int wr = w >> 1, wc = w & 1;                      // wr in [0,4), wc in [0,2)

  auto stage = [&](int buf, int t) {
    const _Float16* ga = Ab + (size_t)rA * LDA + t * 32 + sk;
    const _Float16* gb = Bb + (size_t)rB * LDB + t * 32 + sk;
    _Float16* la = As + buf * ASZ + (w * 32) * 32;
    _Float16* lb = Bs + buf * BSZ + (w * 16) * 32;
    dma16(ga, la);
    dma16(ga + 16 * LDA, la + 16 * 32);
    dma16(gb, lb);
  };
  auto compute = [&](int buf) {
    const _Float16* A0 = As + buf * ASZ;
    const _Float16* B0 = Bs + buf * BSZ;
    f16x8 a[4];
#pragma unroll
    for (int m = 0; m < 4; ++m)
      a[m] = *(const f16x8*)(A0 + (wr * 64 + m * 16 + fr) * 32 + fsw);
#pragma unroll
    for (int n = 0; n < 4; ++n) {
      f16x8 bn = *(const f16x8*)(B0 + (wc * 64 + n * 16 + fr) * 32 + fsw);
#pragma unroll
      for (int m = 0; m < 4; ++m)
        acc[m][n] =
            __builtin_amdgcn_mfma_f32_16x16x32_f16(a[m], bn, acc[m][n], 0, 0, 0);
    }
  };

  stage(0, 0);
  stage(1, 1);
  int b0 = 0, b1 = 1, b2 = 2;
#pragma unroll 3
  for (int t = 0; t < NT - 2; ++t) {
    stage(b2, t + 2);
    asm volatile("s_waitcnt vmcnt(6)" ::: "memory");
    __builtin_amdgcn_s_barrier();
    __builtin_amdgcn_sched_barrier(0);
    compute(b0);
    __builtin_amdgcn_s_barrier();
    int tmp = b0; b0 = b1; b1 = b2; b2 = tmp;
  }
  asm volatile("s_waitcnt vmcnt(3)" ::: "memory");
  __builtin_amdgcn_s_barrier();
  __builtin_amdgcn_sched_barrier(0);
  compute(b0);
  __builtin_amdgcn_s_barrier();
  asm volatile("s_waitcnt vmcnt(0)" ::: "memory");
  __builtin_amdgcn_s_barrier();
  __builtin_amdgcn_sched_barrier(0);
  compute(b1);
}

// bijective XCD swizzle (nwg % 8 == 0); N-tile 128, M-tile 256
#define SWZ_DECODE(GX, GY)                                          \
  int lin = blockIdx.x + (GX) * (blockIdx.y + (GY) * blockIdx.z);   \
  constexpr int NWG = (GX) * (GY) * B_;                             \
  int w8 = (lin & 7) * (NWG / 8) + (lin >> 3);                      \
  int j0 = (w8 % (GX)) * 128;                                       \
  int t_ = w8 / (GX);                                               \
  int i0 = (t_ % (GY)) * 256;                                       \
  int b = t_ / (GY);

// ---------------------------------------------------------------------------
// K1: qp[b][q][pd] = sum_d q16[q][d] * W16[pd][d]. grid (PD/128, Q/256, B)
// ---------------------------------------------------------------------------
__global__ __launch_bounds__(512, 4) void k1_proj(
    const _Float16* __restrict__ q16, const _Float16* __restrict__ W16,
    _Float16* __restrict__ qp) {
  __shared__ alignas(16) _Float16 As[3 * 256 * 32];
  __shared__ alignas(16) _Float16 Bs[3 * 128 * 32];
  SWZ_DECODE(PD_ / 128, Q_ / 256)
  int tid = threadIdx.x, w = tid >> 6, l = tid & 63;
  f32x4 acc[4][4];
#pragma unroll
  for (int m = 0; m < 4; ++m)
#pragma unroll
    for (int n = 0; n < 4; ++n) acc[m][n] = (f32x4){0.f, 0.f, 0.f, 0.f};
  gemm_core<QD_ / 32, QD_, QD_>(q16 + (size_t)b * Q_ * QD_ + (size_t)i0 * QD_,
                                W16 + (size_t)j0 * QD_, As, Bs, acc, w, l);
  int wr = w >> 1, wc = w & 1, fr = l & 15, fq = l >> 4;
  _Float16* O = qp + (size_t)b * Q_ * PD_;
#pragma unroll
  for (int m = 0; m < 4; ++m) {
    int rl = wr * 64 + m * 16 + fq * 4;
#pragma unroll
    for (int n = 0; n < 4; ++n) {
      int cl = wc * 64 + n * 16 + fr;
#pragma unroll
      for (int r = 0; r < 4; ++r)
        O[(size_t)(i0 + rl + r) * PD_ + j0 + cl] = (_Float16)acc[m][n][r];
    }
  }
}

// ---------------------------------------------------------------------------
// K2: aff[b][p][q] = sum_d p16[p][d] * qp[q][d]. grid (Q/128, P/256, B)
// Epilogue: fp32 aff write + BOTH softmax-stat partials from fp32 accs:
//   col partials (over 256 p-rows, pmask) -> pmax/psum_part[z = i0/256] (4)
//   row partials (over 128 q-cols, qmask) -> rpm/rps[zj = j0/128] (4)
// ---------------------------------------------------------------------------
__global__ __launch_bounds__(512, 4) void k2_aff(
    const _Float16* __restrict__ p16, const _Float16* __restrict__ qp,
    const int* __restrict__ pmask, const int* __restrict__ qmask,
    float* __restrict__ aff, float* __restrict__ pmax_part,
    float* __restrict__ psum_part, float* __restrict__ rpm,
    float* __restrict__ rps) {
  __shared__ alignas(16) _Float16 As[3 * 256 * 32];
  __shared__ alignas(16) _Float16 Bs[3 * 128 * 32];
  SWZ_DECODE(Q_ / 128, P_ / 256)
  int tid = threadIdx.x, w = tid >> 6, l = tid & 63;
  f32x4 acc[4][4];
#pragma unroll
  for (int m = 0; m < 4; ++m)
#pragma unroll
    for (int n = 0; n < 4; ++n) acc[m][n] = (f32x4){0.f, 0.f, 0.f, 0.f};
  gemm_core<PD_ / 32, PD_, PD_>(p16 + (size_t)b * P_ * PD_ + (size_t)i0 * PD_,
                                qp + (size_t)b * Q_ * PD_ + (size_t)j0 * PD_,
                                As, Bs, acc, w, l);
  int wr = w >> 1, wc = w & 1, fr = l & 15, fq = l >> 4;
  float* Cb = aff + (size_t)b * P_ * Q_;
#pragma unroll
  for (int m = 0; m < 4; ++m) {
    int rl = wr * 64 + m * 16 + fq * 4;
#pragma unroll
    for (int n = 0; n < 4; ++n) {
      int cl = wc * 64 + n * 16 + fr;
#pragma unroll
      for (int r = 0; r < 4; ++r)
        Cb[(size_t)(i0 + rl + r) * Q_ + j0 + cl] = acc[m][n][r];
    }
  }
  // ---- fused softmax stat partials ----
  const int* pmb = pmask + b * P_ + i0;
  unsigned pmbits = 0;
#pragma unroll
  for (int m = 0; m < 4; ++m)
#pragma unroll
    for (int r = 0; r < 4; ++r)
      pmbits |= (pmb[wr * 64 + m * 16 + fq * 4 + r] ? 1u : 0u) << (m * 4 + r);
  int qmv[4];
  {
    const int* qmb = qmask + b * Q_ + j0 + wc * 64 + fr;
#pragma unroll
    for (int n = 0; n < 4; ++n) qmv[n] = qmb[n * 16];
  }
  __syncthreads();
  float* scr = (float*)As;  // 8KB scratch in dead LDS
  float* cm_ = scr;         // [4][128]
  float* cs_ = scr + 512;
  float* rm_ = scr + 1024;  // [2][256]
  float* rs_ = scr + 1536;

  // col partials: each thread reduces its 16 rows; shfl over fq; 4 wr bands
#pragma unroll
  for (int n = 0; n < 4; ++n) {
    float ml = -1e30f;
#pragma unroll
    for (int m = 0; m < 4; ++m)
#pragma unroll
      for (int r = 0; r < 4; ++r) {
        float v = ((pmbits >> (m * 4 + r)) & 1) ? HUGE_NEG : acc[m][n][r];
        ml = fmaxf(ml, v);
      }
    float sl = 0.f;
#pragma unroll
    for (int m = 0; m < 4; ++m)
#pragma unroll
      for (int r = 0; r < 4; ++r) {
        float v = ((pmbits >> (m * 4 + r)) & 1) ? HUGE_NEG : acc[m][n][r];
        sl += __expf(v - ml);
      }
#pragma unroll
    for (int off = 16; off <= 32; off <<= 1) {
      float om = __shfl_xor(ml, off);
      float os = __shfl_xor(sl, off);
      float nm = fmaxf(ml, om);
      sl = sl * __expf(ml - nm) + os * __expf(om - nm);
      ml = nm;
    }
    if (fq == 0) {
      int col = wc * 64 + n * 16 + fr;
      cm_[wr * 128 + col] = ml;
      cs_[wr * 128 + col] = sl;
    }
  }
  // row partials: reduce over 4 cols in-reg, shfl over fr; 2 wc bands
#pragma unroll
  for (int m = 0; m < 4; ++m)
#pragma unroll
    for (int r = 0; r < 4; ++r) {
      float ml = -1e30f;
#pragma unroll
      for (int n = 0; n < 4; ++n) {
        float v = qmv[n] ? HUGE_NEG : acc[m][n][r];
        ml = fmaxf(ml, v);
      }
      float sl = 0.f;
#pragma unroll
      for (int n = 0; n < 4; ++n) {
        float v = qmv[n] ? HUGE_NEG : acc[m][n][r];
        sl += __expf(v - ml);
      }
#pragma unroll
      for (int off = 1; off <= 8; off <<= 1) {
        float om = __shfl_xor(ml, off);
        float os = __shfl_xor(sl, off);
        float nm = fmaxf(ml, om);
        sl = sl * __expf(ml - nm) + os * __expf(om - nm);
        ml = nm;
      }
      if (fr == 0) {
        int row = wr * 64 + m * 16 + fq * 4 + r;
        rm_[wc * 256 + row] = ml;
        rs_[wc * 256 + row] = sl;
      }
    }
  __syncthreads();
  if (tid < 128) {  // col merge: 4 wr bands -> one partial per (b, z, q)
    float nm = fmaxf(fmaxf(cm_[tid], cm_[128 + tid]),
                     fmaxf(cm_[256 + tid], cm_[384 + tid]));
    float ns = cs_[tid] * __expf(cm_[tid] - nm) +
               cs_[128 + tid] * __expf(cm_[128 + tid] - nm) +
               cs_[256 + tid] * __expf(cm_[256 + tid] - nm) +
               cs_[384 + tid] * __expf(cm_[384 + tid] - nm);
    int z = i0 >> 8;
    pmax_part[(b * 4 + z) * Q_ + j0 + tid] = nm;
    psum_part[(b * 4 + z) * Q_ + j0 + tid] = ns;
  } else if (tid >= 256) {  // row merge: 2 wc bands
    int t = tid - 256;
    float m0 = rm_[t], m1 = rm_[256 + t];
    float s0 = rs_[t], s1 = rs_[256 + t];
    float nm = fmaxf(m0, m1);
    float ns = s0 * __expf(m0 - nm) + s1 * __expf(m1 - nm);
    int zj = j0 >> 7;
    rpm[(b * 4 + zj) * P_ + i0 + t] = nm;
    rps[(b * 4 + zj) * P_ + i0 + t] = ns;
  }
}

// ---------------------------------------------------------------------------
// K4: out2[b][q][d] = sum_p WQ[q][p] * pT[d][p]  (cinv pre-folded into WQ)
// Also writes candT[b][768+d][q] fp16. grid (PD/128, Q/256, B)
// ---------------------------------------------------------------------------
__global__ __launch_bounds__(512, 4) void k4_attn(
    const _Float16* __restrict__ WQ, const _Float16* __restrict__ pT,
    float* __restrict__ out2, _Float16* __restrict__ candT) {
  __shared__ alignas(16) _Float16 As[3 * 256 * 32];
  __shared__ alignas(16) _Float16 Bs[3 * 128 * 32];
  SWZ_DECODE(PD_ / 128, Q_ / 256)
  int tid = threadIdx.x, w = tid >> 6, l = tid & 63;
  f32x4 acc[4][4];
#pragma unroll
  for (int m = 0; m < 4; ++m)
#pragma unroll
    for (int n = 0; n < 4; ++n) acc[m][n] = (f32x4){0.f, 0.f, 0.f, 0.f};
  gemm_core<P_ / 32, P_, P_>(WQ + (size_t)b * Q_ * P_ + (size_t)i0 * P_,
                             pT + (size_t)b * PD_ * P_ + (size_t)j0 * P_, As,
                             Bs, acc, w, l);
  int wr = w >> 1, wc = w & 1, fr = l & 15, fq = l >> 4;
  float* Cb = out2 + (size_t)b * Q_ * PD_;
  _Float16* Tb = candT + (size_t)b * CD_ * Q_;
#pragma unroll
  for (int m = 0; m < 4; ++m) {
    int rl = wr * 64 + m * 16 + fq * 4;
#pragma unroll
    for (int n = 0; n < 4; ++n) {
      int cl = wc * 64 + n * 16 + fr;
      f16x4 cv;
#pragma unroll
      for (int r = 0; r < 4; ++r) {
        float v = acc[m][n][r];
        Cb[(size_t)(i0 + rl + r) * PD_ + j0 + cl] = v;
        cv[r] = (_Float16)v;
      }
      *(f16x4*)(Tb + (size_t)(QD_ + j0 + cl) * Q_ + i0 + rl) = cv;
    }
  }
}

// ---------------------------------------------------------------------------
// K5: out1[b][p][c] = sum_q WP[p][q] * candT[c][q]  (rinv pre-folded into WP)
// grid (CD/128, P/256, B)
// ---------------------------------------------------------------------------
__global__ __launch_bounds__(512, 4) void k5_attn(
    const _Float16* __restrict__ WP, const _Float16* __restrict__ candT,
    float* __restrict__ out1) {
  __shared__ alignas(16) _Float16 As[3 * 256 * 32];
  __shared__ alignas(16) _Float16 Bs[3 * 128 * 32];
  SWZ_DECODE(CD_ / 128, P_ / 256)
  int tid = threadIdx.x, w = tid >> 6, l = tid & 63;
  f32x4 acc[4][4];
#pragma unroll
  for (int m = 0; m < 4; ++m)
#pragma unroll
    for (int n = 0; n < 4; ++n) acc[m][n] = (f32x4){0.f, 0.f, 0.f, 0.f};
  gemm_core<Q_ / 32, Q_, Q_>(WP + (size_t)b * P_ * Q_ + (size_t)i0 * Q_,
                             candT + (size_t)b * CD_ * Q_ + (size_t)j0 * Q_, As,
                             Bs, acc, w, l);
  int wr = w >> 1, wc = w & 1, fr = l & 15, fq = l >> 4;
  float* Cb = out1 + (size_t)b * P_ * CD_;
#pragma unroll
  for (int m = 0; m < 4; ++m) {
    int rl = wr * 64 + m * 16 + fq * 4;
#pragma unroll
    for (int n = 0; n < 4; ++n) {
      int cl = wc * 64 + n * 16 + fr;
#pragma unroll
      for (int r = 0; r < 4; ++r)
        Cb[(size_t)(i0 + rl + r) * CD_ + j0 + cl] = acc[m][n][r];
    }
  }
}

// ---------------------------------------------------------------------------
extern "C" void kernel_launch(void* const* d_in, const int* in_sizes, int n_in,
                              void* d_out, int out_size, void* d_ws,
                              size_t ws_size, hipStream_t stream) {
  const float* p = (const float*)d_in[0];
  const float* q = (const float*)d_in[1];
  const int* pmask = (const int*)d_in[2];
  const int* qmask = (const int*)d_in[3];
  const float* W = (const float*)d_in[4];
  float* out = (float*)d_out;

  char* ws = (char*)d_ws;
  size_t off = 0;
  auto alloc = [&](size_t bytes) {
    void* r = ws + off;
    off += (bytes + 255) & ~(size_t)255;
    return r;
  };
  _Float16* q16 = (_Float16*)alloc((size_t)B_ * Q_ * QD_ * 2);
  _Float16* p16 = (_Float16*)alloc((size_t)B_ * P_ * PD_ * 2);
  _Float16* pT = (_Float16*)alloc((size_t)B_ * PD_ * P_ * 2);
  _Float16* candT = (_Float16*)alloc((size_t)B_ * CD_ * Q_ * 2);
  _Float16* W16 = (_Float16*)alloc((size_t)PD_ * QD_ * 2);
  _Float16* qp16 = (_Float16*)alloc((size_t)B_ * Q_ * PD_ * 2);
  float* aff = (float*)alloc((size_t)B_ * P_ * Q_ * 4);
  _Float16* WP = (_Float16*)alloc((size_t)B_ * P_ * Q_ * 2);
  _Float16* WQ = (_Float16*)alloc((size_t)B_ * Q_ * P_ * 2);
  float* pmax_part = (float*)alloc((size_t)B_ * 4 * Q_ * 4);
  float* psum_part = (float*)alloc((size_t)B_ * 4 * Q_ * 4);
  float* rpm = (float*)alloc((size_t)B_ * 4 * P_ * 4);
  float* rps = (float*)alloc((size_t)B_ * 4 * P_ * 4);

  float* out1 = out;                          // [B,P,1536]
  float* out2 = out + (size_t)B_ * P_ * CD_;  // [B,Q,768]

  // 1. input preparation (fused convert + transpose; W convert only)
  k_cvt<<<PD_ * QD_ / 8 / 256, 256, 0, stream>>>(W, W16, PD_ * QD_ / 8);
  k_prep<<<dim3(Q_ / 64, QD_ / 64, B_), 256, 0, stream>>>(
      q, q16, candT, Q_, QD_, (size_t)CD_ * Q_);  // candT cols 0..767
  k_prep<<<dim3(P_ / 64, PD_ / 64, B_), 256, 0, stream>>>(
      p, p16, pT, P_, PD_, (size_t)PD_ * P_);
  // 2. K1 projection (8-wave 256x128 core)
  k1_proj<<<dim3(PD_ / 128, Q_ / 256, B_), 512, 0, stream>>>(q16, W16, qp16);
  // 3. K2 affinity + fused row/col stat partials
  k2_aff<<<dim3(Q_ / 128, P_ / 256, B_), 512, 0, stream>>>(
      p16, qp16, pmask, qmask, aff, pmax_part, psum_part, rpm, rps);
  // 4. fused weights (merges partials in-block; one aff read -> WP + WQ)
  k_w<<<dim3(P_ / 64, Q_ / 64, B_), 256, 0, stream>>>(
      aff, pmask, qmask, rpm, rps, pmax_part, psum_part, WP, WQ);
  // 5. K4 -> out2 + candT upper half
  k4_attn<<<dim3(PD_ / 128, Q_ / 256, B_), 512, 0, stream>>>(WQ, pT, out2,
                                                             candT);
  // 6. K5 -> out1
  k5_attn<<<dim3(CD_ / 128, P_ / 256, B_), 512, 0, stream>>>(WP, candT, out1);
}